// Round 7
// baseline (7907.819 us; speedup 1.0000x reference)
//
#include <hip/hip_runtime.h>

typedef unsigned short u16;
typedef __bf16 bf16x8 __attribute__((ext_vector_type(8)));
typedef unsigned short u16x8 __attribute__((ext_vector_type(8)));
typedef float f32x4 __attribute__((ext_vector_type(4)));

#define B_    64
#define NTOK  197
#define DIM   768
#define NH    12
#define LAY   12
#define HID_  3072
#define MROWS (B_*NTOK)   // 12608

#define EPI_BF16  0
#define EPI_PROJ  2
#define EPI_GELU  3
#define EPI_FC2   4
#define EPI_PATCH 5

__device__ __forceinline__ u16 f2bf(float f) {
  unsigned u = __float_as_uint(f);
  u += 0x7FFFu + ((u >> 16) & 1u);          // RNE
  return (u16)(u >> 16);
}
__device__ __forceinline__ float bf2f(u16 h) {
  return __uint_as_float(((unsigned)h) << 16);
}

__device__ __forceinline__ void gld_lds16(const void* g, void* l) {
  __builtin_amdgcn_global_load_lds(
      (const __attribute__((address_space(1))) void*)g,
      (__attribute__((address_space(3))) void*)l, 16, 0, 0);
}

// ---------------- diagnostic fill ----------------
__global__ void fill_k(float* __restrict__ o, float v, int n) {
  int i = blockIdx.x * blockDim.x + threadIdx.x;
  const int st = gridDim.x * blockDim.x;
  for (; i < n; i += st) o[i] = v;
}

// ---------------- f32 -> bf16 convert ----------------
__global__ void cvt_bf16(const float* __restrict__ in, u16* __restrict__ out, int n4) {
  int i = blockIdx.x * blockDim.x + threadIdx.x;
  const int st = gridDim.x * blockDim.x;
  for (; i < n4; i += st) {
    float4 v = ((const float4*)in)[i];
    ushort4 o;
    o.x = f2bf(v.x); o.y = f2bf(v.y); o.z = f2bf(v.z); o.w = f2bf(v.w);
    ((ushort4*)out)[i] = o;
  }
}

// ---------------- fused 4-way f32 -> bf16 convert ----------------
__global__ void cvt4_k(const float* __restrict__ s0, const float* __restrict__ s1,
                       const float* __restrict__ s2, const float* __restrict__ s3,
                       u16* __restrict__ d0, u16* __restrict__ d1,
                       u16* __restrict__ d2, u16* __restrict__ d3,
                       int n0, int n1, int n2, int n3)   // float4 counts
{
  int i = blockIdx.x * blockDim.x + threadIdx.x;
  const int st = gridDim.x * blockDim.x;
  const int total = n0 + n1 + n2 + n3;
  for (; i < total; i += st) {
    const float* s; u16* d; int j = i;
    if (j < n0) { s = s0; d = d0; }
    else { j -= n0;
      if (j < n1) { s = s1; d = d1; }
      else { j -= n1;
        if (j < n2) { s = s2; d = d2; }
        else { j -= n2; s = s3; d = d3; } } }
    float4 v = ((const float4*)s)[j];
    ushort4 o;
    o.x = f2bf(v.x); o.y = f2bf(v.y); o.z = f2bf(v.z); o.w = f2bf(v.w);
    ((ushort4*)d)[j] = o;
  }
}

// ---------------- im2col for patch conv ----------------
__global__ void im2col_k(const float* __restrict__ x, u16* __restrict__ out) {
  int i = blockIdx.x * blockDim.x + threadIdx.x;
  const int st = gridDim.x * blockDim.x;
  const int total = 12544 * 768;
  for (; i < total; i += st) {
    int row = i / 768, col = i - row * 768;
    int b = row / 196, pr = row - b * 196;
    int py = pr / 14, px = pr - py * 14;
    int cin = col >> 8, rr = col & 255;
    int ky = rr >> 4, kx = rr & 15;
    out[i] = f2bf(x[((b * 3 + cin) * 224 + py * 16 + ky) * 224 + px * 16 + kx]);
  }
}

// ---------------- cls token + pos embed row 0 ----------------
__global__ void clspos_k(const float* __restrict__ cls, const float* __restrict__ pos,
                         float* __restrict__ t) {
  int i = blockIdx.x * blockDim.x + threadIdx.x;
  if (i >= B_ * DIM) return;
  int b = i / DIM, d = i - b * DIM;
  t[(size_t)b * NTOK * DIM + d] = cls[d] + pos[d];
}

// ---------------- modulation (fp32, exact) ----------------
__global__ __launch_bounds__(256)
void modk(const float* __restrict__ lat, const float* __restrict__ w,
          const float* __restrict__ bias, float* __restrict__ out, int ldb)
{
  __shared__ float ls[32][65];
  __shared__ float wsm[64][33];
  const int tid = threadIdx.x;
  const int mat = blockIdx.y;
  const int n0 = blockIdx.x * 64;
  const int nl = tid & 63;
  const int bg = tid >> 6;
  float acc[16];
  #pragma unroll
  for (int j = 0; j < 16; ++j) acc[j] = 0.f;
  for (int k0 = 0; k0 < 768; k0 += 32) {
    __syncthreads();
    #pragma unroll
    for (int i = 0; i < 8; ++i) {
      int idx = tid + i * 256;
      int rr = idx >> 5, kk = idx & 31;
      ls[kk][rr]  = lat[rr * 768 + k0 + kk];
      wsm[rr][kk] = w[((size_t)mat * 768 + n0 + rr) * 768 + k0 + kk];
    }
    __syncthreads();
    #pragma unroll 4
    for (int kk = 0; kk < 32; ++kk) {
      float wv = wsm[nl][kk];
      #pragma unroll
      for (int j = 0; j < 16; ++j)
        acc[j] += ls[kk][bg * 16 + j] * wv;
    }
  }
  const float EQS = 0.036084391824351615f;    // 1/sqrt(768)
  const float* bs = bias + (size_t)mat * 768 + n0;
  #pragma unroll
  for (int j = 0; j < 16; ++j) {
    int b = bg * 16 + j;
    out[(size_t)b * ldb + mat * 768 + n0 + nl] = acc[j] * EQS + bs[nl];
  }
}

// ---------------- SelfModulatedLayerNorm apply ----------------
__global__ __launch_bounds__(256)
void smln_k(const float* __restrict__ x,
            const float* __restrict__ gamma, const float* __restrict__ beta, int ldg,
            float* __restrict__ oF, u16* __restrict__ oB)
{
  const int row = blockIdx.x;
  const int tid = threadIdx.x;
  const float* xr = x + (size_t)row * DIM;
  float v0 = xr[tid], v1 = xr[tid + 256], v2 = xr[tid + 512];
  float s1 = v0 + v1 + v2;
  float s2 = v0 * v0 + v1 * v1 + v2 * v2;
  #pragma unroll
  for (int o = 32; o; o >>= 1) { s1 += __shfl_xor(s1, o); s2 += __shfl_xor(s2, o); }
  __shared__ float rs[8];
  const int lane = tid & 63, wv = tid >> 6;
  if (lane == 0) { rs[wv] = s1; rs[4 + wv] = s2; }
  __syncthreads();
  s1 = rs[0] + rs[1] + rs[2] + rs[3];
  s2 = rs[4] + rs[5] + rs[6] + rs[7];
  const float mean = s1 * (1.f / 768.f);
  const float var  = s2 * (1.f / 768.f) - mean * mean;
  const float rstd = rsqrtf(var + 1e-3f);
  const int b = row / NTOK;
  const float* g  = gamma + (size_t)b * ldg;
  const float* be = beta  + (size_t)b * ldg;
  const size_t base = (size_t)row * DIM;
  float vv[3] = {v0, v1, v2};
  #pragma unroll
  for (int j = 0; j < 3; ++j) {
    int d = tid + j * 256;
    float y = (vv[j] - mean) * rstd;
    y = y * (1.f + g[d]) + be[d];
    oF[base + d] = y;
    if (oB) oB[base + d] = f2bf(y);
  }
}

// ---------------- MFMA attention: one block per (b,h) ----------------
__global__ __launch_bounds__(256)
void attn_k(const u16* __restrict__ qkv, u16* __restrict__ ao)
{
  __shared__ u16 Ks[208 * 68];
  __shared__ u16 Vt[64 * 226];
  __shared__ u16 Ps[4][16 * 228];
  const int bh = blockIdx.x;
  const int b = bh / NH, h = bh - (bh / NH) * NH;
  const int tid = threadIdx.x;
  const int lane = tid & 63, wv = tid >> 6;
  const int lr = lane & 15, kg = lane >> 4;
  const size_t tb = (size_t)(b * NTOK) * 2304 + h * 64;

  for (int t = tid; t < 1576; t += 256) {
    int n = t >> 3, c = t & 7;
    *(u16x8*)&Ks[n * 68 + c * 8] =
        *(const u16x8*)&qkv[tb + (size_t)n * 2304 + 768 + c * 8];
  }
  for (int t = tid; t < 1576; t += 256) {
    int n = t >> 3, dc = t & 7;
    u16x8 v = *(const u16x8*)&qkv[tb + (size_t)n * 2304 + 1536 + dc * 8];
    #pragma unroll
    for (int j = 0; j < 8; ++j) Vt[(dc * 8 + j) * 226 + n] = v[j];
  }
  for (int i = tid; i < 11 * 68; i += 256) Ks[197 * 68 + i] = 0;
  for (int i = tid; i < 64 * 29; i += 256) {
    int d = i / 29, c = i - d * 29;
    Vt[d * 226 + 197 + c] = 0;
  }
  for (int i = tid; i < 4 * 16 * 20; i += 256) {
    int w = i / 320, rm = i - w * 320, r = rm / 20, c = rm - r * 20;
    Ps[w][r * 228 + 208 + c] = 0;
  }
  __syncthreads();

  const f32x4 z4 = {0.f, 0.f, 0.f, 0.f};
  u16* pw = Ps[wv];

  for (int qt = wv; qt < 13; qt += 4) {
    const int q0 = qt * 16;
    const int qrow = min(q0 + lr, 196);
    const bf16x8 aq0 = *(const bf16x8*)&qkv[tb + (size_t)qrow * 2304 + kg * 8];
    const bf16x8 aq1 = *(const bf16x8*)&qkv[tb + (size_t)qrow * 2304 + 32 + kg * 8];

    f32x4 acc[13];
    #pragma unroll
    for (int ct = 0; ct < 13; ++ct) acc[ct] = z4;
    #pragma unroll
    for (int ct = 0; ct < 13; ++ct) {
      const bf16x8 bk0 = *(const bf16x8*)&Ks[(ct * 16 + lr) * 68 + kg * 8];
      const bf16x8 bk1 = *(const bf16x8*)&Ks[(ct * 16 + lr) * 68 + 32 + kg * 8];
      acc[ct] = __builtin_amdgcn_mfma_f32_16x16x32_bf16(aq0, bk0, acc[ct], 0, 0, 0);
      acc[ct] = __builtin_amdgcn_mfma_f32_16x16x32_bf16(aq1, bk1, acc[ct], 0, 0, 0);
    }

    float mx[4], sm[4], inv[4];
    #pragma unroll
    for (int r = 0; r < 4; ++r) mx[r] = -1e30f;
    #pragma unroll
    for (int ct = 0; ct < 13; ++ct)
      #pragma unroll
      for (int r = 0; r < 4; ++r) {
        float s = acc[ct][r] * 0.125f;
        if (ct * 16 + lr >= 197) s = -1e30f;
        acc[ct][r] = s;
        mx[r] = fmaxf(mx[r], s);
      }
    #pragma unroll
    for (int o = 1; o < 16; o <<= 1)
      #pragma unroll
      for (int r = 0; r < 4; ++r) mx[r] = fmaxf(mx[r], __shfl_xor(mx[r], o));
    #pragma unroll
    for (int r = 0; r < 4; ++r) sm[r] = 0.f;
    #pragma unroll
    for (int ct = 0; ct < 13; ++ct)
      #pragma unroll
      for (int r = 0; r < 4; ++r) {
        float p = __expf(acc[ct][r] - mx[r]);
        acc[ct][r] = p;
        sm[r] += p;
      }
    #pragma unroll
    for (int o = 1; o < 16; o <<= 1)
      #pragma unroll
      for (int r = 0; r < 4; ++r) sm[r] += __shfl_xor(sm[r], o);
    #pragma unroll
    for (int r = 0; r < 4; ++r) inv[r] = 1.f / sm[r];

    #pragma unroll
    for (int ct = 0; ct < 13; ++ct)
      #pragma unroll
      for (int r = 0; r < 4; ++r)
        pw[(kg * 4 + r) * 228 + ct * 16 + lr] = f2bf(acc[ct][r]);
    asm volatile("s_waitcnt lgkmcnt(0)" ::: "memory");
    __builtin_amdgcn_sched_barrier(0);

    f32x4 accO[4];
    #pragma unroll
    for (int dt = 0; dt < 4; ++dt) accO[dt] = z4;
    #pragma unroll
    for (int kt = 0; kt < 7; ++kt) {
      const bf16x8 ap = *(const bf16x8*)&pw[lr * 228 + kt * 32 + kg * 8];
      #pragma unroll
      for (int dt = 0; dt < 4; ++dt) {
        const bf16x8 bv = *(const bf16x8*)&Vt[(dt * 16 + lr) * 226 + kt * 32 + kg * 8];
        accO[dt] = __builtin_amdgcn_mfma_f32_16x16x32_bf16(ap, bv, accO[dt], 0, 0, 0);
      }
    }

    #pragma unroll
    for (int r = 0; r < 4; ++r) {
      const int q = q0 + kg * 4 + r;
      if (q < NTOK) {
        const size_t base = ((size_t)(b * NTOK + q)) * DIM + h * 64;
        #pragma unroll
        for (int dt = 0; dt < 4; ++dt)
          ao[base + dt * 16 + lr] = f2bf(accO[dt][r] * inv[r]);
      }
    }
  }
}

// ---------------- bf16 MFMA GEMM, C = A[M,K] * W[N,K]^T ----------------
// BM=256 x BN=64, 4 waves, BK=32, double-buffered LDS with T3-minimum 2-phase
// schedule (1 raw barrier + counted-overlap vmcnt per K-step), XCD-swizzled 1D
// grid (tn-inner), LDS-transposed epilogue -> full-128B-line vector stores.
template<int EPI>
__global__ __launch_bounds__(256)
void gemm_bt(const u16* __restrict__ A, int lda,
             const u16* __restrict__ Bw, int ldb,
             int M, int K, int gn,
             const float* __restrict__ bias,
             const float* __restrict__ res,
             float* __restrict__ outF, u16* __restrict__ outB, int ldo,
             const float* __restrict__ aux)
{
  __shared__ u16 As[2][8192];   // [256 rows][32 k] x2
  __shared__ u16 Bs[2][2048];   // [64 rows][32 k] x2
  const int tid = threadIdx.x;
  const int lane = tid & 63, wv = tid >> 6;
  const int lr = lane & 15, kg = lane >> 4;

  // bijective XCD swizzle; v = tm*gn + tn (tn fastest)
  const int nwg = gridDim.x;
  const int qq = nwg >> 3, rr = nwg & 7;
  const int xcd = blockIdx.x & 7, loc = blockIdx.x >> 3;
  const int v = (xcd < rr ? xcd * (qq + 1) : rr * (qq + 1) + (xcd - rr) * qq) + loc;
  const int tm = v / gn, tn = v - tm * gn;

  // A staging sources: chunk c -> LDS row c>>2, slot (c&3)^(row&3)
  const u16* aS[4];
  #pragma unroll
  for (int i = 0; i < 4; ++i) {
    int c = tid + i * 256;
    int row = c >> 2, q2 = (c & 3) ^ (row & 3);
    int am = tm * 256 + row; if (am >= M) am = M - 1;
    aS[i] = A + (size_t)am * lda + q2 * 8;
  }
  const int rb = tid >> 2, qb = (tid & 3) ^ (rb & 3);
  const u16* bS = Bw + (size_t)(tn * 64 + rb) * ldb + qb * 8;
  u16* aD0 = &As[0][wv * 512];
  u16* aD1 = &As[1][wv * 512];
  u16* bD0 = &Bs[0][wv * 512];
  u16* bD1 = &Bs[1][wv * 512];

  f32x4 acc[4][4];
  const f32x4 z = {0.f, 0.f, 0.f, 0.f};
  #pragma unroll
  for (int m = 0; m < 4; ++m)
    #pragma unroll
    for (int n = 0; n < 4; ++n) acc[m][n] = z;

#define STAGE0(ko) do { gld_lds16(aS[0]+(ko), aD0); gld_lds16(aS[1]+(ko), aD0+2048); \
                        gld_lds16(aS[2]+(ko), aD0+4096); gld_lds16(aS[3]+(ko), aD0+6144); \
                        gld_lds16(bS+(ko), bD0); } while(0)
#define STAGE1(ko) do { gld_lds16(aS[0]+(ko), aD1); gld_lds16(aS[1]+(ko), aD1+2048); \
                        gld_lds16(aS[2]+(ko), aD1+4096); gld_lds16(aS[3]+(ko), aD1+6144); \
                        gld_lds16(bS+(ko), bD1); } while(0)
#define KPHASE(buf) do { \
    bf16x8 af[4], bfr[4]; \
    _Pragma("unroll") \
    for (int m = 0; m < 4; ++m) { \
      int row = wv * 64 + m * 16 + lr; \
      af[m] = *(const bf16x8*)&As[buf][row * 32 + (((kg ^ row) & 3) << 3)]; \
    } \
    _Pragma("unroll") \
    for (int n = 0; n < 4; ++n) { \
      int row = n * 16 + lr; \
      bfr[n] = *(const bf16x8*)&Bs[buf][row * 32 + (((kg ^ row) & 3) << 3)]; \
    } \
    _Pragma("unroll") \
    for (int m = 0; m < 4; ++m) \
      _Pragma("unroll") \
      for (int n = 0; n < 4; ++n) \
        acc[m][n] = __builtin_amdgcn_mfma_f32_16x16x32_bf16(af[m], bfr[n], acc[m][n], 0, 0, 0); \
  } while(0)
#define PHASE_END() do { \
    asm volatile("s_waitcnt lgkmcnt(0)" ::: "memory"); \
    asm volatile("s_waitcnt vmcnt(0)" ::: "memory"); \
    __builtin_amdgcn_s_barrier(); \
    __builtin_amdgcn_sched_barrier(0); \
  } while(0)

  const int KT = K >> 5;        // even in all uses (24 or 96)
  STAGE0(0);
  PHASE_END();
  for (int kt = 0; kt < KT; kt += 2) {
    STAGE1((kt + 1) * 32);      // prefetch odd tile
    KPHASE(0);
    PHASE_END();
    if (kt + 2 < KT) STAGE0((kt + 2) * 32);  // prefetch next even tile
    KPHASE(1);
    PHASE_END();
  }

  // ---- epilogue: LDS transpose -> full-line vector stores ----
  const int gr0 = tm * 256 + wv * 64;
  const int gc0 = tn * 64;
  if constexpr (EPI == EPI_BF16 || EPI == EPI_GELU) {
    u16* T = (u16*)As + wv * 1152;            // [16][72] per wave
    #pragma unroll
    for (int m = 0; m < 4; ++m) {
      #pragma unroll
      for (int n = 0; n < 4; ++n) {
        #pragma unroll
        for (int r = 0; r < 4; ++r) {
          float val = acc[m][n][r];
          if constexpr (EPI == EPI_GELU) {
            float u = val + bias[gc0 + n * 16 + lr];
            val = 0.5f * u * (1.f + erff(u * 0.70710678118654752f));
          }
          T[(kg * 4 + r) * 72 + n * 16 + lr] = f2bf(val);
        }
      }
      asm volatile("s_waitcnt lgkmcnt(0)" ::: "memory");
      __builtin_amdgcn_sched_barrier(0);
      #pragma unroll
      for (int half = 0; half < 2; ++half) {
        int row = (lane >> 3) + half * 8;
        int c8 = lane & 7;
        u16x8 vv = *(const u16x8*)&T[row * 72 + c8 * 8];
        int gr = gr0 + m * 16 + row;
        if (gr < M) *(u16x8*)&outB[(size_t)gr * ldo + gc0 + c8 * 8] = vv;
      }
      asm volatile("s_waitcnt lgkmcnt(0)" ::: "memory");   // reads done before T reuse
      __builtin_amdgcn_sched_barrier(0);
    }
  } else {
    float* T = (float*)As + wv * 1088;        // [16][68] per wave
    #pragma unroll
    for (int m = 0; m < 4; ++m) {
      #pragma unroll
      for (int n = 0; n < 4; ++n)
        #pragma unroll
        for (int r = 0; r < 4; ++r)
          T[(kg * 4 + r) * 68 + n * 16 + lr] = acc[m][n][r];
      asm volatile("s_waitcnt lgkmcnt(0)" ::: "memory");
      __builtin_amdgcn_sched_barrier(0);
      #pragma unroll
      for (int qu = 0; qu < 4; ++qu) {
        int row = (lane >> 4) + qu * 4;
        int c4 = lane & 15;
        f32x4 vv = *(const f32x4*)&T[row * 68 + c4 * 4];
        int gr = gr0 + m * 16 + row;
        int gc = gc0 + c4 * 4;
        if (gr < M) {
          f32x4 bv = *(const f32x4*)&bias[gc];
          if constexpr (EPI == EPI_PROJ) {
            size_t o = (size_t)gr * ldo + gc;
            f32x4 rv = *(const f32x4*)&res[o];
            f32x4 ov = vv + bv + 2.f * rv;
            *(f32x4*)&outF[o] = ov;
          } else if constexpr (EPI == EPI_FC2) {
            size_t o = (size_t)gr * ldo + gc;
            f32x4 rv = *(const f32x4*)&res[o];
            f32x4 ov = vv + bv + rv;
            *(f32x4*)&outF[o] = ov;
          } else {  // EPI_PATCH
            int pb = gr / 196, pp = gr - pb * 196;
            size_t o = ((size_t)pb * NTOK + 1 + pp) * DIM + gc;
            f32x4 av = *(const f32x4*)&aux[(size_t)(1 + pp) * DIM + gc];
            f32x4 ov;
            #pragma unroll
            for (int j = 0; j < 4; ++j) ov[j] = sinf(vv[j] + bv[j]) + av[j];
            *(f32x4*)&outF[o] = ov;
          }
        }
      }
      asm volatile("s_waitcnt lgkmcnt(0)" ::: "memory");
      __builtin_amdgcn_sched_barrier(0);
    }
  }
#undef STAGE0
#undef STAGE1
#undef KPHASE
#undef PHASE_END
}

// ---------------- host ----------------
extern "C" void kernel_launch(void* const* d_in, const int* in_sizes, int n_in,
                              void* d_out, int out_size, void* d_ws, size_t ws_size,
                              hipStream_t stream)
{
  (void)in_sizes; (void)n_in;
  const float* X     = (const float*)d_in[0];
  const float* LAT   = (const float*)d_in[1];
  const float* CONVW = (const float*)d_in[2];
  const float* CONVB = (const float*)d_in[3];
  const float* CLS   = (const float*)d_in[4];
  const float* POS   = (const float*)d_in[5];
  const float* G1W   = (const float*)d_in[6];
  const float* G1B   = (const float*)d_in[7];
  const float* B1W   = (const float*)d_in[8];
  const float* B1B   = (const float*)d_in[9];
  const float* QKVW  = (const float*)d_in[10];
  const float* PROJW = (const float*)d_in[11];
  const float* PROJB = (const float*)d_in[12];
  const float* G2W   = (const float*)d_in[13];
  const float* G2B   = (const float*)d_in[14];
  const float* B2W   = (const float*)d_in[15];
  const float* B2B   = (const float*)d_in[16];
  const float* FC1W  = (const float*)d_in[17];
  const float* FC1B  = (const float*)d_in[18];
  const float* FC2W  = (const float*)d_in[19];
  const float* FC2B  = (const float*)d_in[20];
  const float* GNW   = (const float*)d_in[21];
  const float* GNB   = (const float*)d_in[22];
  const float* BNW   = (const float*)d_in[23];
  const float* BNB   = (const float*)d_in[24];

  char* p = (char*)d_ws;
  auto carve = [&](size_t bytes) { char* r = p; p += (bytes + 255) & ~(size_t)255; return r; };

  // union buffer: patches (pre-loop) / qkvb (qkv->attn) / hb (fc1->fc2)
  char* Ubuf  = carve((size_t)MROWS * HID_ * 2);            // 77.5 MB
  u16* patches = (u16*)Ubuf;
  u16* qkvb    = (u16*)Ubuf;
  u16* hb      = (u16*)Ubuf;
  u16* wconv  = (u16*)carve((size_t)768 * 768 * 2);
  u16* wqkv_l = (u16*)carve((size_t)2304 * 768 * 2);
  u16* wproj_l= (u16*)carve((size_t)768 * 768 * 2);
  u16* wfc1_l = (u16*)carve((size_t)3072 * 768 * 2);
  u16* wfc2_l = (u16*)carve((size_t)768 * 3072 * 2);
  float* tf   = (float*)carve((size_t)MROWS * 768 * 4);
  float* xnf  = (float*)carve((size_t)MROWS * 768 * 4);
  u16* xnb    = (u16*)carve((size_t)MROWS * 768 * 2);
  u16* aob    = (u16*)carve((size_t)MROWS * 768 * 2);
  float* gam1 = (float*)carve((size_t)B_ * 9216 * 4);
  float* bet1 = (float*)carve((size_t)B_ * 9216 * 4);
  float* gam2 = (float*)carve((size_t)B_ * 9216 * 4);
  float* bet2 = (float*)carve((size_t)B_ * 9216 * 4);
  float* gamN = (float*)carve((size_t)B_ * 768 * 4);
  float* betN = (float*)carve((size_t)B_ * 768 * 4);

  // canary: if guard returns, d_out stays 1e9 -> visible failure mode
  fill_k<<<1, 64, 0, stream>>>((float*)d_out, 1e9f, 1);
  if ((size_t)(p - (char*)d_ws) > ws_size) {
    fill_k<<<256, 256, 0, stream>>>((float*)d_out, 1e9f, out_size);
    return;
  }

  // modulation gammas/betas (fp32, exact)
  modk<<<dim3(12, 12), 256, 0, stream>>>(LAT, G1W, G1B, gam1, 9216);
  modk<<<dim3(12, 12), 256, 0, stream>>>(LAT, B1W, B1B, bet1, 9216);
  modk<<<dim3(12, 12), 256, 0, stream>>>(LAT, G2W, G2B, gam2, 9216);
  modk<<<dim3(12, 12), 256, 0, stream>>>(LAT, B2W, B2B, bet2, 9216);
  modk<<<dim3(12, 1),  256, 0, stream>>>(LAT, GNW, GNB, gamN, 768);
  modk<<<dim3(12, 1),  256, 0, stream>>>(LAT, BNW, BNB, betN, 768);

  // patch embed
  {
    int n4 = 768 * 768 / 4;
    cvt_bf16<<<(n4 + 255) / 256, 256, 0, stream>>>(CONVW, wconv, n4);
  }
  im2col_k<<<4096, 256, 0, stream>>>(X, patches);
  gemm_bt<EPI_PATCH><<<49 * 12, 256, 0, stream>>>(patches, 768, wconv, 768, 12544, 768, 12,
                                                  CONVB, nullptr, tf, nullptr, 768, POS);
  clspos_k<<<(B_ * DIM + 255) / 256, 256, 0, stream>>>(CLS, POS, tf);

  const int n4_qkv = 2304 * 768 / 4, n4_pro = 768 * 768 / 4, n4_fc = 3072 * 768 / 4;
  for (int l = 0; l < LAY; ++l) {
    cvt4_k<<<4096, 256, 0, stream>>>(QKVW + (size_t)l * 2304 * 768, PROJW + (size_t)l * 768 * 768,
                                     FC1W + (size_t)l * 3072 * 768, FC2W + (size_t)l * 768 * 3072,
                                     wqkv_l, wproj_l, wfc1_l, wfc2_l,
                                     n4_qkv, n4_pro, n4_fc, n4_fc);
    smln_k<<<MROWS, 256, 0, stream>>>(tf, gam1 + l * 768, bet1 + l * 768, 9216, xnf, xnb);
    gemm_bt<EPI_BF16><<<50 * 36, 256, 0, stream>>>(xnb, 768, wqkv_l, 768, MROWS, 768, 36,
                                                   nullptr, nullptr, nullptr, qkvb, 2304, nullptr);
    attn_k<<<B_ * NH, 256, 0, stream>>>(qkvb, aob);
    gemm_bt<EPI_PROJ><<<50 * 12, 256, 0, stream>>>(aob, 768, wproj_l, 768, MROWS, 768, 12,
                                                   PROJB + l * 768, xnf, tf, nullptr, 768, nullptr);
    smln_k<<<MROWS, 256, 0, stream>>>(tf, gam2 + l * 768, bet2 + l * 768, 9216, xnf, xnb);
    gemm_bt<EPI_GELU><<<50 * 48, 256, 0, stream>>>(xnb, 768, wfc1_l, 768, MROWS, 768, 48,
                                                   FC1B + l * 3072, nullptr, nullptr, hb, 3072, nullptr);
    gemm_bt<EPI_FC2><<<50 * 12, 256, 0, stream>>>(hb, 3072, wfc2_l, 3072, MROWS, 3072, 12,
                                                  FC2B + l * 768, xnf, tf, nullptr, 768, nullptr);
  }
  smln_k<<<MROWS, 256, 0, stream>>>(tf, gamN, betN, 768, (float*)d_out, nullptr);
}

// Round 8
// 6068.963 us; speedup vs baseline: 1.3030x; 1.3030x over previous
//
#include <hip/hip_runtime.h>

typedef unsigned short u16;
typedef __bf16 bf16x8 __attribute__((ext_vector_type(8)));
typedef unsigned short u16x8 __attribute__((ext_vector_type(8)));
typedef float f32x4 __attribute__((ext_vector_type(4)));

#define B_    64
#define NTOK  197
#define DIM   768
#define NH    12
#define LAY   12
#define HID_  3072
#define MROWS (B_*NTOK)   // 12608

#define EPI_BF16  0
#define EPI_PROJ  2
#define EPI_GELU  3
#define EPI_FC2   4
#define EPI_PATCH 5

__device__ __forceinline__ u16 f2bf(float f) {
  unsigned u = __float_as_uint(f);
  u += 0x7FFFu + ((u >> 16) & 1u);          // RNE
  return (u16)(u >> 16);
}
__device__ __forceinline__ float bf2f(u16 h) {
  return __uint_as_float(((unsigned)h) << 16);
}

__device__ __forceinline__ void gld_lds16(const void* g, void* l) {
  __builtin_amdgcn_global_load_lds(
      (const __attribute__((address_space(1))) void*)g,
      (__attribute__((address_space(3))) void*)l, 16, 0, 0);
}

// ---------------- diagnostic fill ----------------
__global__ void fill_k(float* __restrict__ o, float v, int n) {
  int i = blockIdx.x * blockDim.x + threadIdx.x;
  const int st = gridDim.x * blockDim.x;
  for (; i < n; i += st) o[i] = v;
}

// ---------------- f32 -> bf16 convert ----------------
__global__ void cvt_bf16(const float* __restrict__ in, u16* __restrict__ out, int n4) {
  int i = blockIdx.x * blockDim.x + threadIdx.x;
  const int st = gridDim.x * blockDim.x;
  for (; i < n4; i += st) {
    float4 v = ((const float4*)in)[i];
    ushort4 o;
    o.x = f2bf(v.x); o.y = f2bf(v.y); o.z = f2bf(v.z); o.w = f2bf(v.w);
    ((ushort4*)out)[i] = o;
  }
}

// ---------------- fused 4-way f32 -> bf16 convert ----------------
__global__ void cvt4_k(const float* __restrict__ s0, const float* __restrict__ s1,
                       const float* __restrict__ s2, const float* __restrict__ s3,
                       u16* __restrict__ d0, u16* __restrict__ d1,
                       u16* __restrict__ d2, u16* __restrict__ d3,
                       int n0, int n1, int n2, int n3)   // float4 counts
{
  int i = blockIdx.x * blockDim.x + threadIdx.x;
  const int st = gridDim.x * blockDim.x;
  const int total = n0 + n1 + n2 + n3;
  for (; i < total; i += st) {
    const float* s; u16* d; int j = i;
    if (j < n0) { s = s0; d = d0; }
    else { j -= n0;
      if (j < n1) { s = s1; d = d1; }
      else { j -= n1;
        if (j < n2) { s = s2; d = d2; }
        else { j -= n2; s = s3; d = d3; } } }
    float4 v = ((const float4*)s)[j];
    ushort4 o;
    o.x = f2bf(v.x); o.y = f2bf(v.y); o.z = f2bf(v.z); o.w = f2bf(v.w);
    ((ushort4*)d)[j] = o;
  }
}

// ---------------- im2col for patch conv ----------------
__global__ void im2col_k(const float* __restrict__ x, u16* __restrict__ out) {
  int i = blockIdx.x * blockDim.x + threadIdx.x;
  const int st = gridDim.x * blockDim.x;
  const int total = 12544 * 768;
  for (; i < total; i += st) {
    int row = i / 768, col = i - row * 768;
    int b = row / 196, pr = row - b * 196;
    int py = pr / 14, px = pr - py * 14;
    int cin = col >> 8, rr = col & 255;
    int ky = rr >> 4, kx = rr & 15;
    out[i] = f2bf(x[((b * 3 + cin) * 224 + py * 16 + ky) * 224 + px * 16 + kx]);
  }
}

// ---------------- cls token + pos embed row 0 ----------------
__global__ void clspos_k(const float* __restrict__ cls, const float* __restrict__ pos,
                         float* __restrict__ t) {
  int i = blockIdx.x * blockDim.x + threadIdx.x;
  if (i >= B_ * DIM) return;
  int b = i / DIM, d = i - b * DIM;
  t[(size_t)b * NTOK * DIM + d] = cls[d] + pos[d];
}

// ---------------- modulation (fp32, exact) ----------------
__global__ __launch_bounds__(256)
void modk(const float* __restrict__ lat, const float* __restrict__ w,
          const float* __restrict__ bias, float* __restrict__ out, int ldb)
{
  __shared__ float ls[32][65];
  __shared__ float wsm[64][33];
  const int tid = threadIdx.x;
  const int mat = blockIdx.y;
  const int n0 = blockIdx.x * 64;
  const int nl = tid & 63;
  const int bg = tid >> 6;
  float acc[16];
  #pragma unroll
  for (int j = 0; j < 16; ++j) acc[j] = 0.f;
  for (int k0 = 0; k0 < 768; k0 += 32) {
    __syncthreads();
    #pragma unroll
    for (int i = 0; i < 8; ++i) {
      int idx = tid + i * 256;
      int rr = idx >> 5, kk = idx & 31;
      ls[kk][rr]  = lat[rr * 768 + k0 + kk];
      wsm[rr][kk] = w[((size_t)mat * 768 + n0 + rr) * 768 + k0 + kk];
    }
    __syncthreads();
    #pragma unroll 4
    for (int kk = 0; kk < 32; ++kk) {
      float wv = wsm[nl][kk];
      #pragma unroll
      for (int j = 0; j < 16; ++j)
        acc[j] += ls[kk][bg * 16 + j] * wv;
    }
  }
  const float EQS = 0.036084391824351615f;    // 1/sqrt(768)
  const float* bs = bias + (size_t)mat * 768 + n0;
  #pragma unroll
  for (int j = 0; j < 16; ++j) {
    int b = bg * 16 + j;
    out[(size_t)b * ldb + mat * 768 + n0 + nl] = acc[j] * EQS + bs[nl];
  }
}

// ---------------- SelfModulatedLayerNorm apply ----------------
__global__ __launch_bounds__(256)
void smln_k(const float* __restrict__ x,
            const float* __restrict__ gamma, const float* __restrict__ beta, int ldg,
            float* __restrict__ oF, u16* __restrict__ oB)
{
  const int row = blockIdx.x;
  const int tid = threadIdx.x;
  const float* xr = x + (size_t)row * DIM;
  float v0 = xr[tid], v1 = xr[tid + 256], v2 = xr[tid + 512];
  float s1 = v0 + v1 + v2;
  float s2 = v0 * v0 + v1 * v1 + v2 * v2;
  #pragma unroll
  for (int o = 32; o; o >>= 1) { s1 += __shfl_xor(s1, o); s2 += __shfl_xor(s2, o); }
  __shared__ float rs[8];
  const int lane = tid & 63, wv = tid >> 6;
  if (lane == 0) { rs[wv] = s1; rs[4 + wv] = s2; }
  __syncthreads();
  s1 = rs[0] + rs[1] + rs[2] + rs[3];
  s2 = rs[4] + rs[5] + rs[6] + rs[7];
  const float mean = s1 * (1.f / 768.f);
  const float var  = s2 * (1.f / 768.f) - mean * mean;
  const float rstd = rsqrtf(var + 1e-3f);
  const int b = row / NTOK;
  const float* g  = gamma + (size_t)b * ldg;
  const float* be = beta  + (size_t)b * ldg;
  const size_t base = (size_t)row * DIM;
  float vv[3] = {v0, v1, v2};
  #pragma unroll
  for (int j = 0; j < 3; ++j) {
    int d = tid + j * 256;
    float y = (vv[j] - mean) * rstd;
    y = y * (1.f + g[d]) + be[d];
    oF[base + d] = y;
    if (oB) oB[base + d] = f2bf(y);
  }
}

// ---------------- MFMA attention: one block per (b,h) ----------------
__global__ __launch_bounds__(256)
void attn_k(const u16* __restrict__ qkv, u16* __restrict__ ao)
{
  __shared__ u16 Ks[208 * 68];
  __shared__ u16 Vt[64 * 226];
  __shared__ u16 Ps[4][16 * 228];
  const int bh = blockIdx.x;
  const int b = bh / NH, h = bh - (bh / NH) * NH;
  const int tid = threadIdx.x;
  const int lane = tid & 63, wv = tid >> 6;
  const int lr = lane & 15, kg = lane >> 4;
  const size_t tb = (size_t)(b * NTOK) * 2304 + h * 64;

  for (int t = tid; t < 1576; t += 256) {
    int n = t >> 3, c = t & 7;
    *(u16x8*)&Ks[n * 68 + c * 8] =
        *(const u16x8*)&qkv[tb + (size_t)n * 2304 + 768 + c * 8];
  }
  for (int t = tid; t < 1576; t += 256) {
    int n = t >> 3, dc = t & 7;
    u16x8 v = *(const u16x8*)&qkv[tb + (size_t)n * 2304 + 1536 + dc * 8];
    #pragma unroll
    for (int j = 0; j < 8; ++j) Vt[(dc * 8 + j) * 226 + n] = v[j];
  }
  for (int i = tid; i < 11 * 68; i += 256) Ks[197 * 68 + i] = 0;
  for (int i = tid; i < 64 * 29; i += 256) {
    int d = i / 29, c = i - d * 29;
    Vt[d * 226 + 197 + c] = 0;
  }
  for (int i = tid; i < 4 * 16 * 20; i += 256) {
    int w = i / 320, rm = i - w * 320, r = rm / 20, c = rm - r * 20;
    Ps[w][r * 228 + 208 + c] = 0;
  }
  __syncthreads();

  const f32x4 z4 = {0.f, 0.f, 0.f, 0.f};
  u16* pw = Ps[wv];

  for (int qt = wv; qt < 13; qt += 4) {
    const int q0 = qt * 16;
    const int qrow = min(q0 + lr, 196);
    const bf16x8 aq0 = *(const bf16x8*)&qkv[tb + (size_t)qrow * 2304 + kg * 8];
    const bf16x8 aq1 = *(const bf16x8*)&qkv[tb + (size_t)qrow * 2304 + 32 + kg * 8];

    f32x4 acc[13];
    #pragma unroll
    for (int ct = 0; ct < 13; ++ct) acc[ct] = z4;
    #pragma unroll
    for (int ct = 0; ct < 13; ++ct) {
      const bf16x8 bk0 = *(const bf16x8*)&Ks[(ct * 16 + lr) * 68 + kg * 8];
      const bf16x8 bk1 = *(const bf16x8*)&Ks[(ct * 16 + lr) * 68 + 32 + kg * 8];
      acc[ct] = __builtin_amdgcn_mfma_f32_16x16x32_bf16(aq0, bk0, acc[ct], 0, 0, 0);
      acc[ct] = __builtin_amdgcn_mfma_f32_16x16x32_bf16(aq1, bk1, acc[ct], 0, 0, 0);
    }

    float mx[4], sm[4], inv[4];
    #pragma unroll
    for (int r = 0; r < 4; ++r) mx[r] = -1e30f;
    #pragma unroll
    for (int ct = 0; ct < 13; ++ct)
      #pragma unroll
      for (int r = 0; r < 4; ++r) {
        float s = acc[ct][r] * 0.125f;
        if (ct * 16 + lr >= 197) s = -1e30f;
        acc[ct][r] = s;
        mx[r] = fmaxf(mx[r], s);
      }
    #pragma unroll
    for (int o = 1; o < 16; o <<= 1)
      #pragma unroll
      for (int r = 0; r < 4; ++r) mx[r] = fmaxf(mx[r], __shfl_xor(mx[r], o));
    #pragma unroll
    for (int r = 0; r < 4; ++r) sm[r] = 0.f;
    #pragma unroll
    for (int ct = 0; ct < 13; ++ct)
      #pragma unroll
      for (int r = 0; r < 4; ++r) {
        float p = __expf(acc[ct][r] - mx[r]);
        acc[ct][r] = p;
        sm[r] += p;
      }
    #pragma unroll
    for (int o = 1; o < 16; o <<= 1)
      #pragma unroll
      for (int r = 0; r < 4; ++r) sm[r] += __shfl_xor(sm[r], o);
    #pragma unroll
    for (int r = 0; r < 4; ++r) inv[r] = 1.f / sm[r];

    #pragma unroll
    for (int ct = 0; ct < 13; ++ct)
      #pragma unroll
      for (int r = 0; r < 4; ++r)
        pw[(kg * 4 + r) * 228 + ct * 16 + lr] = f2bf(acc[ct][r]);
    asm volatile("s_waitcnt lgkmcnt(0)" ::: "memory");
    __builtin_amdgcn_sched_barrier(0);

    f32x4 accO[4];
    #pragma unroll
    for (int dt = 0; dt < 4; ++dt) accO[dt] = z4;
    #pragma unroll
    for (int kt = 0; kt < 7; ++kt) {
      const bf16x8 ap = *(const bf16x8*)&pw[lr * 228 + kt * 32 + kg * 8];
      #pragma unroll
      for (int dt = 0; dt < 4; ++dt) {
        const bf16x8 bv = *(const bf16x8*)&Vt[(dt * 16 + lr) * 226 + kt * 32 + kg * 8];
        accO[dt] = __builtin_amdgcn_mfma_f32_16x16x32_bf16(ap, bv, accO[dt], 0, 0, 0);
      }
    }

    #pragma unroll
    for (int r = 0; r < 4; ++r) {
      const int q = q0 + kg * 4 + r;
      if (q < NTOK) {
        const size_t base = ((size_t)(b * NTOK + q)) * DIM + h * 64;
        #pragma unroll
        for (int dt = 0; dt < 4; ++dt)
          ao[base + dt * 16 + lr] = f2bf(accO[dt][r] * inv[r]);
      }
    }
  }
}

// ---------------- bf16 MFMA GEMM, C = A[M,K] * W[N,K]^T ----------------
// BM=BN=128, 4 waves (2x2 of 64x64), BK=32, 3-buffer LDS ring with counted
// vmcnt(4) at tile boundaries (prefetch rides through barriers; never drained
// in the main loop). Slot XOR (kg ^ (row&3) ^ ((row>>2)&3)) -> 2-way max bank
// aliasing. XCD-swizzled 1D grid (tn-inner). LDS-transposed vector-store
// epilogue (fixes write amplification).
template<int EPI>
__global__ __launch_bounds__(256)
void gemm_bt(const u16* __restrict__ A, int lda,
             const u16* __restrict__ Bw, int ldb,
             int M, int K, int gn,
             const float* __restrict__ bias,
             const float* __restrict__ res,
             float* __restrict__ outF, u16* __restrict__ outB, int ldo,
             const float* __restrict__ aux)
{
  __shared__ u16 SA[3][4096];   // [128 rows][32 k] x3 ring
  __shared__ u16 SB[3][4096];
  const int tid = threadIdx.x;
  const int lane = tid & 63, wv = tid >> 6;
  const int lr = lane & 15, kg = lane >> 4;
  const int wm = wv >> 1, wn = wv & 1;

  // bijective XCD swizzle; v = tm*gn + tn (tn fastest)
  const int nwg = gridDim.x;
  const int qq = nwg >> 3, rr2 = nwg & 7;
  const int xcd = blockIdx.x & 7, loc = blockIdx.x >> 3;
  const int v = (xcd < rr2 ? xcd * (qq + 1) : rr2 * (qq + 1) + (xcd - rr2) * qq) + loc;
  const int tm = v / gn, tn = v - tm * gn;

  // staging sources: chunk c -> LDS row c>>2, phys slot c&3 holds logical
  // k-group q = (c&3) ^ (row&3) ^ ((row>>2)&3)
  const int c0 = tid, c1 = tid + 256;
  const int r0 = c0 >> 2, q0 = (c0 & 3) ^ (r0 & 3) ^ ((r0 >> 2) & 3);
  const int r1 = c1 >> 2, q1 = (c1 & 3) ^ (r1 & 3) ^ ((r1 >> 2) & 3);
  int am0 = tm * 128 + r0; if (am0 >= M) am0 = M - 1;
  int am1 = tm * 128 + r1; if (am1 >= M) am1 = M - 1;
  const u16* aS0 = A  + (size_t)am0 * lda + q0 * 8;
  const u16* aS1 = A  + (size_t)am1 * lda + q1 * 8;
  const u16* bS0 = Bw + (size_t)(tn * 128 + r0) * ldb + q0 * 8;
  const u16* bS1 = Bw + (size_t)(tn * 128 + r1) * ldb + q1 * 8;

  f32x4 acc[4][4];
  const f32x4 z = {0.f, 0.f, 0.f, 0.f};
  #pragma unroll
  for (int m = 0; m < 4; ++m)
    #pragma unroll
    for (int n = 0; n < 4; ++n) acc[m][n] = z;

#define STG(buf, ko) do { \
    u16* aD = &SA[buf][wv * 512]; u16* bD = &SB[buf][wv * 512]; \
    gld_lds16(aS0 + (ko), aD);        gld_lds16(aS1 + (ko), aD + 2048); \
    gld_lds16(bS0 + (ko), bD);        gld_lds16(bS1 + (ko), bD + 2048); \
  } while (0)

  const int KT = K >> 5;   // 24 or 96
  // prologue: stage tiles 0 and 1; wait tile 0 landed (tile 1 rides)
  STG(0, 0);
  STG(1, 32);
  asm volatile("s_waitcnt vmcnt(4)" ::: "memory");
  __builtin_amdgcn_s_barrier();
  __builtin_amdgcn_sched_barrier(0);

  for (int t = 0; t < KT; ++t) {
    const int buf = t % 3;
    if (t) {
      asm volatile("s_waitcnt lgkmcnt(0)" ::: "memory");   // my reads of old buf done
      __builtin_amdgcn_sched_barrier(0);
      if (t + 1 < KT) asm volatile("s_waitcnt vmcnt(4)" ::: "memory");  // tile t landed, t+1 rides
      else            asm volatile("s_waitcnt vmcnt(0)" ::: "memory");
      __builtin_amdgcn_s_barrier();
      __builtin_amdgcn_sched_barrier(0);
    }
    if (t + 2 < KT) STG((t + 2) % 3, (t + 2) * 32);        // prefetch, never drained
    bf16x8 af[4], bfr[4];
    #pragma unroll
    for (int m = 0; m < 4; ++m) {
      int row = wm * 64 + m * 16 + lr;
      af[m] = *(const bf16x8*)&SA[buf][row * 32 + (((kg ^ row ^ (row >> 2)) & 3) << 3)];
    }
    #pragma unroll
    for (int n = 0; n < 4; ++n) {
      int row = wn * 64 + n * 16 + lr;
      bfr[n] = *(const bf16x8*)&SB[buf][row * 32 + (((kg ^ row ^ (row >> 2)) & 3) << 3)];
    }
    #pragma unroll
    for (int m = 0; m < 4; ++m)
      #pragma unroll
      for (int n = 0; n < 4; ++n)
        acc[m][n] = __builtin_amdgcn_mfma_f32_16x16x32_bf16(af[m], bfr[n], acc[m][n], 0, 0, 0);
  }
#undef STG
  __syncthreads();   // all waves done with LDS before epilogue reuse

  // ---- epilogue: LDS transpose -> full-line vector stores ----
  const int gr0 = tm * 128 + wm * 64;
  const int gc0 = tn * 128 + wn * 64;
  if constexpr (EPI == EPI_BF16 || EPI == EPI_GELU) {
    u16* T = (u16*)SA + wv * 1152;            // [16][72] per wave
    #pragma unroll
    for (int m = 0; m < 4; ++m) {
      #pragma unroll
      for (int n = 0; n < 4; ++n) {
        #pragma unroll
        for (int r = 0; r < 4; ++r) {
          float val = acc[m][n][r];
          if constexpr (EPI == EPI_GELU) {
            float u = val + bias[gc0 + n * 16 + lr];
            val = 0.5f * u * (1.f + erff(u * 0.70710678118654752f));
          }
          T[(kg * 4 + r) * 72 + n * 16 + lr] = f2bf(val);
        }
      }
      asm volatile("s_waitcnt lgkmcnt(0)" ::: "memory");
      __builtin_amdgcn_sched_barrier(0);
      #pragma unroll
      for (int half = 0; half < 2; ++half) {
        int row = (lane >> 3) + half * 8;
        int c8 = lane & 7;
        u16x8 vv = *(const u16x8*)&T[row * 72 + c8 * 8];
        int gr = gr0 + m * 16 + row;
        if (gr < M) *(u16x8*)&outB[(size_t)gr * ldo + gc0 + c8 * 8] = vv;
      }
      asm volatile("s_waitcnt lgkmcnt(0)" ::: "memory");   // reads done before T reuse
      __builtin_amdgcn_sched_barrier(0);
    }
  } else {
    float* T = (float*)SA + wv * 1088;        // [16][68] per wave
    #pragma unroll
    for (int m = 0; m < 4; ++m) {
      #pragma unroll
      for (int n = 0; n < 4; ++n)
        #pragma unroll
        for (int r = 0; r < 4; ++r)
          T[(kg * 4 + r) * 68 + n * 16 + lr] = acc[m][n][r];
      asm volatile("s_waitcnt lgkmcnt(0)" ::: "memory");
      __builtin_amdgcn_sched_barrier(0);
      #pragma unroll
      for (int qu = 0; qu < 4; ++qu) {
        int row = (lane >> 4) + qu * 4;
        int c4 = lane & 15;
        f32x4 vv = *(const f32x4*)&T[row * 68 + c4 * 4];
        int gr = gr0 + m * 16 + row;
        int gc = gc0 + c4 * 4;
        if (gr < M) {
          f32x4 bv = *(const f32x4*)&bias[gc];
          if constexpr (EPI == EPI_PROJ) {
            size_t o = (size_t)gr * ldo + gc;
            f32x4 rv = *(const f32x4*)&res[o];
            f32x4 ov = vv + bv + 2.f * rv;
            *(f32x4*)&outF[o] = ov;
          } else if constexpr (EPI == EPI_FC2) {
            size_t o = (size_t)gr * ldo + gc;
            f32x4 rv = *(const f32x4*)&res[o];
            f32x4 ov = vv + bv + rv;
            *(f32x4*)&outF[o] = ov;
          } else {  // EPI_PATCH
            int pb = gr / 196, pp = gr - pb * 196;
            size_t o = ((size_t)pb * NTOK + 1 + pp) * DIM + gc;
            f32x4 av = *(const f32x4*)&aux[(size_t)(1 + pp) * DIM + gc];
            f32x4 ov;
            #pragma unroll
            for (int j = 0; j < 4; ++j) ov[j] = sinf(vv[j] + bv[j]) + av[j];
            *(f32x4*)&outF[o] = ov;
          }
        }
      }
      asm volatile("s_waitcnt lgkmcnt(0)" ::: "memory");
      __builtin_amdgcn_sched_barrier(0);
    }
  }
}

// ---------------- host ----------------
extern "C" void kernel_launch(void* const* d_in, const int* in_sizes, int n_in,
                              void* d_out, int out_size, void* d_ws, size_t ws_size,
                              hipStream_t stream)
{
  (void)in_sizes; (void)n_in;
  const float* X     = (const float*)d_in[0];
  const float* LAT   = (const float*)d_in[1];
  const float* CONVW = (const float*)d_in[2];
  const float* CONVB = (const float*)d_in[3];
  const float* CLS   = (const float*)d_in[4];
  const float* POS   = (const float*)d_in[5];
  const float* G1W   = (const float*)d_in[6];
  const float* G1B   = (const float*)d_in[7];
  const float* B1W   = (const float*)d_in[8];
  const float* B1B   = (const float*)d_in[9];
  const float* QKVW  = (const float*)d_in[10];
  const float* PROJW = (const float*)d_in[11];
  const float* PROJB = (const float*)d_in[12];
  const float* G2W   = (const float*)d_in[13];
  const float* G2B   = (const float*)d_in[14];
  const float* B2W   = (const float*)d_in[15];
  const float* B2B   = (const float*)d_in[16];
  const float* FC1W  = (const float*)d_in[17];
  const float* FC1B  = (const float*)d_in[18];
  const float* FC2W  = (const float*)d_in[19];
  const float* FC2B  = (const float*)d_in[20];
  const float* GNW   = (const float*)d_in[21];
  const float* GNB   = (const float*)d_in[22];
  const float* BNW   = (const float*)d_in[23];
  const float* BNB   = (const float*)d_in[24];

  char* p = (char*)d_ws;
  auto carve = [&](size_t bytes) { char* r = p; p += (bytes + 255) & ~(size_t)255; return r; };

  // union buffer: patches (pre-loop) / qkvb (qkv->attn) / hb (fc1->fc2)
  char* Ubuf  = carve((size_t)MROWS * HID_ * 2);            // 77.5 MB
  u16* patches = (u16*)Ubuf;
  u16* qkvb    = (u16*)Ubuf;
  u16* hb      = (u16*)Ubuf;
  u16* wconv  = (u16*)carve((size_t)768 * 768 * 2);
  u16* wqkv_l = (u16*)carve((size_t)2304 * 768 * 2);
  u16* wproj_l= (u16*)carve((size_t)768 * 768 * 2);
  u16* wfc1_l = (u16*)carve((size_t)3072 * 768 * 2);
  u16* wfc2_l = (u16*)carve((size_t)768 * 3072 * 2);
  float* tf   = (float*)carve((size_t)MROWS * 768 * 4);
  float* xnf  = (float*)carve((size_t)MROWS * 768 * 4);
  u16* xnb    = (u16*)carve((size_t)MROWS * 768 * 2);
  u16* aob    = (u16*)carve((size_t)MROWS * 768 * 2);
  float* gam1 = (float*)carve((size_t)B_ * 9216 * 4);
  float* bet1 = (float*)carve((size_t)B_ * 9216 * 4);
  float* gam2 = (float*)carve((size_t)B_ * 9216 * 4);
  float* bet2 = (float*)carve((size_t)B_ * 9216 * 4);
  float* gamN = (float*)carve((size_t)B_ * 768 * 4);
  float* betN = (float*)carve((size_t)B_ * 768 * 4);

  // canary: if guard returns, d_out stays 1e9 -> visible failure mode
  fill_k<<<1, 64, 0, stream>>>((float*)d_out, 1e9f, 1);
  if ((size_t)(p - (char*)d_ws) > ws_size) {
    fill_k<<<256, 256, 0, stream>>>((float*)d_out, 1e9f, out_size);
    return;
  }

  // modulation gammas/betas (fp32, exact)
  modk<<<dim3(12, 12), 256, 0, stream>>>(LAT, G1W, G1B, gam1, 9216);
  modk<<<dim3(12, 12), 256, 0, stream>>>(LAT, B1W, B1B, bet1, 9216);
  modk<<<dim3(12, 12), 256, 0, stream>>>(LAT, G2W, G2B, gam2, 9216);
  modk<<<dim3(12, 12), 256, 0, stream>>>(LAT, B2W, B2B, bet2, 9216);
  modk<<<dim3(12, 1),  256, 0, stream>>>(LAT, GNW, GNB, gamN, 768);
  modk<<<dim3(12, 1),  256, 0, stream>>>(LAT, BNW, BNB, betN, 768);

  // patch embed
  {
    int n4 = 768 * 768 / 4;
    cvt_bf16<<<(n4 + 255) / 256, 256, 0, stream>>>(CONVW, wconv, n4);
  }
  im2col_k<<<4096, 256, 0, stream>>>(X, patches);
  gemm_bt<EPI_PATCH><<<98 * 6, 256, 0, stream>>>(patches, 768, wconv, 768, 12544, 768, 6,
                                                 CONVB, nullptr, tf, nullptr, 768, POS);
  clspos_k<<<(B_ * DIM + 255) / 256, 256, 0, stream>>>(CLS, POS, tf);

  const int n4_qkv = 2304 * 768 / 4, n4_pro = 768 * 768 / 4, n4_fc = 3072 * 768 / 4;
  for (int l = 0; l < LAY; ++l) {
    cvt4_k<<<4096, 256, 0, stream>>>(QKVW + (size_t)l * 2304 * 768, PROJW + (size_t)l * 768 * 768,
                                     FC1W + (size_t)l * 3072 * 768, FC2W + (size_t)l * 768 * 3072,
                                     wqkv_l, wproj_l, wfc1_l, wfc2_l,
                                     n4_qkv, n4_pro, n4_fc, n4_fc);
    smln_k<<<MROWS, 256, 0, stream>>>(tf, gam1 + l * 768, bet1 + l * 768, 9216, xnf, xnb);
    gemm_bt<EPI_BF16><<<99 * 18, 256, 0, stream>>>(xnb, 768, wqkv_l, 768, MROWS, 768, 18,
                                                   nullptr, nullptr, nullptr, qkvb, 2304, nullptr);
    attn_k<<<B_ * NH, 256, 0, stream>>>(qkvb, aob);
    gemm_bt<EPI_PROJ><<<99 * 6, 256, 0, stream>>>(aob, 768, wproj_l, 768, MROWS, 768, 6,
                                                  PROJB + l * 768, xnf, tf, nullptr, 768, nullptr);
    smln_k<<<MROWS, 256, 0, stream>>>(tf, gam2 + l * 768, bet2 + l * 768, 9216, xnf, xnb);
    gemm_bt<EPI_GELU><<<99 * 24, 256, 0, stream>>>(xnb, 768, wfc1_l, 768, MROWS, 768, 24,
                                                   FC1B + l * 3072, nullptr, nullptr, hb, 3072, nullptr);
    gemm_bt<EPI_FC2><<<99 * 6, 256, 0, stream>>>(hb, 3072, wfc2_l, 3072, MROWS, 3072, 6,
                                                 FC2B + l * 768, xnf, tf, nullptr, 768, nullptr);
  }
  smln_k<<<MROWS, 256, 0, stream>>>(tf, gamN, betN, 768, (float*)d_out, nullptr);
}